// Round 13
// baseline (296.276 us; speedup 1.0000x reference)
//
#include <hip/hip_runtime.h>

// 3D reaction-diffusion tumor solver, 160^3 f32 grid, 30 explicit Euler steps.
// R16: scoped-coherence persistent kernel, GPT=2 (2000 blocks) for 2x waves.
//
// R14 post-mortem: BREAKTHROUGH — timed 476 -> 251.7us once kernel_launch had
// ZERO runtime API calls (the occupancy-gate queries failed during graph
// capture and permanently latched the fallback). Device time 186us/dispatch
// (6.2us/step), absmax 0.0039 unchanged. Remaining limiter: Occupancy 42%,
// VALUBusy 26%, fabric 4.15 TB/s (66% of achievable) -> latency-bound, not
// pipe-saturated. R16 doubles wave count: each thread owns a z-PAIR instead
// of a z-quad -> 2000 blocks x 256 thr; launch_bounds(256,8) caps VGPR at 64
// (state halves to 16 regs) -> 8 blocks/CU by regs, 4KB LDS -> 2048 blocks
// co-resident >= 2000 by construction. Deps unchanged {-25,-1,+1,+25}
// (25 blocks per z-slab). All verified machinery kept: monotone relaxed
// agent flags (replay-safe), runtime XCC-id link classification (sc0 own-XCD
// L2 / sc1 cross-XCD via IC), no agent fences in the loop (no L2
// flush/invalidate), triple buffer (out/ws/g_mid) aligned so the last step
// lands in out, API-free plain launch.

#define NX 160
#define NY 160
#define NZ 160
#define NXQ (NX / 4)              // 40 float4 groups per row
#define NPLANE (NX * NY)          // 25600 floats per z-plane
#define NGROUPS (NZ * NY * NXQ)   // 1,024,000 float4 groups

// --- persistent config: 256-thread blocks, z-pairs ---
#define CT_BS 256
#define CT_NTHREADS (NGROUPS / 2)        // 512,000 (2 planes each)
#define CT_NBLOCKS (CT_NTHREADS / CT_BS) // 2000
#define BPK 25                           // blocks per z-pair slab (6400/256)

typedef float f32x4 __attribute__((ext_vector_type(4)));

// ---- sync + buffer state (zero-init at module load) ----
__device__ unsigned int g_flag[CT_NBLOCKS * 16];   // one flag per 64B line
__device__ unsigned int g_xcdmap[CT_NBLOCKS];      // per-block physical XCC id
__device__ __align__(16) float g_mid[NGROUPS * 4]; // third grid buffer

// Scoped-load/store asm (flg = "" / " sc0" / " sc1").
#define GLD4(dst, voff, base, flg) \
    asm volatile("global_load_dwordx4 %0, %1, %2" flg \
                 : "=v"(dst) : "v"(voff), "s"(base))
#define GLD1(dst, voff, base, flg) \
    asm volatile("global_load_dword %0, %1, %2" flg \
                 : "=v"(dst) : "v"(voff), "s"(base))
#define GST4(voff, val, base, flg) \
    asm volatile("global_store_dwordx4 %0, %1, %2" flg \
                 :: "v"(voff), "v"(val), "s"(base) : "memory")

__device__ __forceinline__ f32x4 ld4v(const float* p) {
    return *reinterpret_cast<const f32x4*>(p);
}

// One Euler step for a float4 column (identical FP order to all prior rounds).
__device__ __forceinline__ f32x4 step_cell(
    f32x4 cc, f32x4 ym, f32x4 yp, f32x4 zm, f32x4 zp,
    float xl, float xr, f32x4 tm, float D, float rho, float delta_t)
{
    f32x4 o;
    float lap, g;
    lap = xl    + cc[1] + ym[0] + yp[0] + zm[0] + zp[0] - 6.f * cc[0];
    g   = D * lap + rho * cc[0] * (1.f - cc[0]) - 2.f * tm[0] * cc[0];
    o[0] = fminf(fmaxf(cc[0] + g * delta_t, 0.f), 1.f);
    lap = cc[0] + cc[2] + ym[1] + yp[1] + zm[1] + zp[1] - 6.f * cc[1];
    g   = D * lap + rho * cc[1] * (1.f - cc[1]) - 2.f * tm[1] * cc[1];
    o[1] = fminf(fmaxf(cc[1] + g * delta_t, 0.f), 1.f);
    lap = cc[1] + cc[3] + ym[2] + yp[2] + zm[2] + zp[2] - 6.f * cc[2];
    g   = D * lap + rho * cc[2] * (1.f - cc[2]) - 2.f * tm[2] * cc[2];
    o[2] = fminf(fmaxf(cc[2] + g * delta_t, 0.f), 1.f);
    lap = cc[2] + xr    + ym[3] + yp[3] + zm[3] + zp[3] - 6.f * cc[3];
    g   = D * lap + rho * cc[3] * (1.f - cc[3]) - 2.f * tm[3] * cc[3];
    o[3] = fminf(fmaxf(cc[3] + g * delta_t, 0.f), 1.f);
    return o;
}

// ---------------- scoped-coherence all-steps kernel ----------------
__global__ __launch_bounds__(CT_BS, 8) void therapy_all(
    const float* __restrict__ c_init,
    const float* __restrict__ ther,
    float* __restrict__ out,
    float* __restrict__ ws,
    const float* __restrict__ Dp,
    const float* __restrict__ rhop,
    const float* __restrict__ dtp,
    const int* __restrict__ stepsp)
{
    __shared__ float2 lx[2][CT_BS];   // per-plane {x0 (reader's xr), x3 (xl)}

    // Bijective XCD swizzle (2000 % 8 == 0): each XCD owns 250 contiguous
    // logical blocks = 10 whole z-pair slabs (locality only; correctness
    // comes from the runtime link classification below).
    const int lb = (blockIdx.x & 7) * (CT_NBLOCKS / 8) + (blockIdx.x >> 3);
    const int tx = threadIdx.x;
    const int tid = lb * CT_BS + tx;

    const int xq = tid % NXQ;           // 0..39
    const int t2 = tid / NXQ;
    const int y  = t2 % NY;             // 0..159
    const int k  = lb / BPK;            // z-pair index, block-uniform (0..79)

    const int   steps   = *stepsp;
    const float D       = *Dp;
    const float rho     = *rhop;
    const float delta_t = *dtp / (float)steps;

    const unsigned int fbase =
        __hip_atomic_load(&g_flag[lb * 16], __ATOMIC_RELAXED,
                          __HIP_MEMORY_SCOPE_AGENT);

    const int  offym = (y > 0)        ? -NX : 0;
    const int  offyp = (y < NY - 1)   ?  NX : 0;
    const int  offxl = (xq > 0)       ? -1  : 0;
    const bool mym = (y == 0), myp = (y == NY - 1);
    const bool mxl = (xq == 0), mxr = (xq == NXQ - 1);
    const bool mzm = (k == 0);
    const bool mzp = (k == NZ / 2 - 1);

    const int b0 = ((2 * k) * NY + y) * NX + 4 * xq;   // plane 2k (floats)
    const int b1 = b0 + NPLANE;                        // plane 2k+1

    const unsigned o_c  = (unsigned)b0 * 4u;
    const unsigned o_ym = (unsigned)(b0 + offym) * 4u;
    const unsigned o_yp = (unsigned)(b0 + offyp) * 4u;
    const unsigned o_xl = (unsigned)(b0 + offxl) * 4u;
    const unsigned o_xr = (unsigned)(b0 + (mxr ? 3 : 4)) * 4u;
    const unsigned o_zm = (unsigned)(b0 + (mzm ? 0 : -NPLANE)) * 4u;
    const unsigned o_zp = (unsigned)(b1 + (mzp ? 0 :  NPLANE)) * 4u;

    // Persistent register state (16 VGPRs).
    const f32x4 tv0 = ld4v(ther + b0);
    const f32x4 tv1 = ld4v(ther + b1);
    f32x4 cv0 = ld4v(c_init + b0);
    f32x4 cv1 = ld4v(c_init + b1);

    // ---- prologue: publish physical XCC id, handshake, classify links ----
    unsigned int myx;
    asm volatile("s_getreg_b32 %0, hwreg(HW_REG_XCC_ID)" : "=s"(myx));
    if (tx == 0) {
        __hip_atomic_store(&g_xcdmap[lb], myx, __ATOMIC_RELAXED,
                           __HIP_MEMORY_SCOPE_AGENT);
        asm volatile("s_waitcnt vmcnt(0)" ::: "memory");
        __hip_atomic_store(&g_flag[lb * 16], fbase + 1u, __ATOMIC_RELAXED,
                           __HIP_MEMORY_SCOPE_AGENT);
    }
    if (tx < 4) {
        const int d = (tx == 0) ? -BPK : (tx == 1) ? -1 : (tx == 2) ? 1 : BPK;
        int nb = lb + d;
        nb = nb < 0 ? 0 : (nb >= CT_NBLOCKS ? CT_NBLOCKS - 1 : nb);
        while (__hip_atomic_load(&g_flag[nb * 16], __ATOMIC_RELAXED,
                                 __HIP_MEMORY_SCOPE_AGENT) < fbase + 1u) {
            __builtin_amdgcn_s_sleep(2);
        }
    }
    __syncthreads();

    #define MAPLD(b) __hip_atomic_load(&g_xcdmap[(b)], __ATOMIC_RELAXED, \
                                       __HIP_MEMORY_SCOPE_AGENT)
    const unsigned xm25 = (lb >= BPK)              ? MAPLD(lb - BPK) : myx;
    const unsigned xm1  = (lb >= 1)                ? MAPLD(lb - 1)   : myx;
    const unsigned xp1  = (lb < CT_NBLOCKS - 1)    ? MAPLD(lb + 1)   : myx;
    const unsigned xp25 = (lb < CT_NBLOCKS - BPK)  ? MAPLD(lb + BPK) : myx;

    const bool zmX = (xm25 != myx);
    const bool zpX = (xp25 != myx);
    const bool ymX = (tx < NXQ)          && (xm1 != myx);
    const bool ypX = (tx >= CT_BS - NXQ) && (xp1 != myx);
    const bool xlX = (tx == 0)           && (xm1 != myx);
    const bool xrX = (tx == CT_BS - 1)   && (xp1 != myx);
    const bool stYX = (tx < NXQ && xm1 != myx) ||
                      (tx >= CT_BS - NXQ && xp1 != myx);
    const bool st0X = stYX || zmX;   // plane 2k   read by lb-25 as zp
    const bool st1X = stYX || zpX;   // plane 2k+1 read by lb+25 as zm

    const int OFF = (3 - (steps - 1) % 3) % 3;

    const float* rd = c_init;
    for (int i = 0; i < steps; ++i) {
        const int s = (i + OFF) % 3;
        float* wr = (s == 0) ? out : (s == 1) ? ws : g_mid;

        // A: publish x-exchange values (previous-step cv == rd values)
        lx[0][tx] = make_float2(cv0[0], cv0[3]);
        lx[1][tx] = make_float2(cv1[0], cv1[3]);

        // B: wait for the 4 dependency blocks to have finished step i-1
        if (i > 0 && tx < 4) {
            const int d = (tx == 0) ? -BPK : (tx == 1) ? -1
                        : (tx == 2) ?    1 : BPK;
            int nb = lb + d;
            nb = nb < 0 ? 0 : (nb >= CT_NBLOCKS ? CT_NBLOCKS - 1 : nb);
            const unsigned tgt = fbase + 1u + (unsigned)i;
            while (__hip_atomic_load(&g_flag[nb * 16], __ATOMIC_RELAXED,
                                     __HIP_MEMORY_SCOPE_AGENT) < tgt) {
                __builtin_amdgcn_s_sleep(2);
            }
        }
        __syncthreads();

        // C: neighbor loads (sc0 = own-XCD L2; sc1 = cross-XCD via IC)
        f32x4 ym0, ym1, yp0, yp1, zmg, zpg;
        if (ymX) { GLD4(ym0, o_ym, rd, " sc1"); GLD4(ym1, o_ym + 102400u, rd, " sc1"); }
        else     { GLD4(ym0, o_ym, rd, " sc0"); GLD4(ym1, o_ym + 102400u, rd, " sc0"); }
        if (ypX) { GLD4(yp0, o_yp, rd, " sc1"); GLD4(yp1, o_yp + 102400u, rd, " sc1"); }
        else     { GLD4(yp0, o_yp, rd, " sc0"); GLD4(yp1, o_yp + 102400u, rd, " sc0"); }
        if (zmX) { GLD4(zmg, o_zm, rd, " sc1"); } else { GLD4(zmg, o_zm, rd, " sc0"); }
        if (zpX) { GLD4(zpg, o_zp, rd, " sc1"); } else { GLD4(zpg, o_zp, rd, " sc0"); }
        float xl0, xl1, xr0, xr1;
        if (tx == 0) {
            if (xlX) { GLD1(xl0, o_xl, rd, " sc1"); GLD1(xl1, o_xl + 102400u, rd, " sc1"); }
            else     { GLD1(xl0, o_xl, rd, " sc0"); GLD1(xl1, o_xl + 102400u, rd, " sc0"); }
        } else { xl0 = lx[0][tx - 1].y; xl1 = lx[1][tx - 1].y; }
        if (tx == CT_BS - 1) {
            if (xrX) { GLD1(xr0, o_xr, rd, " sc1"); GLD1(xr1, o_xr + 102400u, rd, " sc1"); }
            else     { GLD1(xr0, o_xr, rd, " sc0"); GLD1(xr1, o_xr + 102400u, rd, " sc0"); }
        } else { xr0 = lx[0][tx + 1].x; xr1 = lx[1][tx + 1].x; }
        asm volatile("s_waitcnt vmcnt(0)" ::: "memory");
        __builtin_amdgcn_sched_barrier(0);

        // D: boundary masks + compute (intra-pair z-faces from registers)
        const f32x4 z4 = {0.f, 0.f, 0.f, 0.f};
        if (mym) { ym0 = z4; ym1 = z4; }
        if (myp) { yp0 = z4; yp1 = z4; }
        if (mzm) zmg = z4;
        if (mzp) zpg = z4;
        if (mxl) { xl0 = 0.f; xl1 = 0.f; }
        if (mxr) { xr0 = 0.f; xr1 = 0.f; }

        const f32x4 n0 = step_cell(cv0, ym0, yp0, zmg, cv1, xl0, xr0, tv0,
                                   D, rho, delta_t);
        const f32x4 n1 = step_cell(cv1, ym1, yp1, cv0, zpg, xl1, xr1, tv1,
                                   D, rho, delta_t);

        // E: stores (interior stay dirty in local L2; cross-read cells sc1)
        if (st0X) { GST4(o_c, n0, wr, " sc1"); } else { GST4(o_c, n0, wr, ""); }
        if (st1X) { GST4(o_c + 102400u, n1, wr, " sc1"); }
        else      { GST4(o_c + 102400u, n1, wr, ""); }

        // F: drain stores (syncthreads emits per-wave vmcnt(0) before
        //    s_barrier) then post progress with a relaxed agent store.
        __syncthreads();
        if (tx == 0) {
            __hip_atomic_store(&g_flag[lb * 16], fbase + 2u + (unsigned)i,
                               __ATOMIC_RELAXED, __HIP_MEMORY_SCOPE_AGENT);
        }

        cv0 = n0;
        cv1 = n1;
        rd = wr;
    }
}

extern "C" void kernel_launch(void* const* d_in, const int* in_sizes, int n_in,
                              void* d_out, int out_size, void* d_ws, size_t ws_size,
                              hipStream_t stream) {
    const float* c_init = (const float*)d_in[0];
    const float* Dp     = (const float*)d_in[1];
    const float* rhop   = (const float*)d_in[2];
    const float* dtp    = (const float*)d_in[3];
    const float* ther   = (const float*)d_in[4];
    const int*   stepsp = (const int*)d_in[5];

    float* out = (float*)d_out;
    float* wsA = (float*)d_ws;   // grid buffer (16.4 MB)

    // NO runtime API calls here (graph-capture-safe). Co-residency is
    // compile-time guaranteed by __launch_bounds__(256,8): 8 blocks/CU x
    // 256 CUs = 2048 >= 2000 launched.
    therapy_all<<<dim3(CT_NBLOCKS), dim3(CT_BS), 0, stream>>>(
        c_init, ther, out, wsA, Dp, rhop, dtp, stepsp);
}

// Round 14
// 234.311 us; speedup vs baseline: 1.2645x; 1.2645x over previous
//
#include <hip/hip_runtime.h>

// 3D reaction-diffusion tumor solver, 160^3 f32 grid, 30 explicit Euler steps.
// R17: scoped-coherence persistent kernel, GPT=4, DOUBLE buffer (ping-pong).
//
// R16 post-mortem: GPT=2 (2000 blocks) RAISED occupancy 42->86% but REGRESSED
// 186->222us device; BW fell 4.15->3.6 TB/s. Not latency-bound: at GPT=4,
// traffic/step (25MB) / 4.15 TB/s = 6.05us ~= observed 6.2us/step -> the
// kernel is FABRIC-TRAFFIC-bound. Revert to GPT=4 and cut traffic at the
// source: the 3-buffer rotation put 8.2MB/XCD against the 4MB/XCD L2, so
// every step's 16.4MB of dirty lines evicted to HBM (WRITE 482MB/dispatch).
// WAR re-derivation: the flag protocol already makes ping-pong safe — at
// step i a block has waited for its 4 deps to FINISH step i-1, and only
// those deps ever read its cells, so its step i-2 data is dead when buffer
// (i%2) is overwritten; deps can't reach step i+1's writes before this
// block posts step i (two-sided skew bound). Triple buffering was
// unnecessary. R17 = R14 verbatim except bufs {out, ws} (step 29 -> out),
// g_mid deleted. Working set 8.2 -> 6.2 MB/XCD.
//
// Kernel otherwise identical to the verified R14: 1000 blocks x 256 thr,
// z-quads (internal z-faces from registers), deps {-25,-1,+1,+25} via
// monotone relaxed agent flags (replay-safe), runtime XCC-id link
// classification (sc0 own-XCD L2 / sc1 cross-XCD via IC), no agent fences
// in the loop, API-free plain launch (graph-capture-safe; co-residency
// compile-time guaranteed by launch_bounds(256,4): >=1024 >= 1000).

#define NX 160
#define NY 160
#define NZ 160
#define NXQ (NX / 4)              // 40 float4 groups per row
#define NPLANE (NX * NY)          // 25600 floats per z-plane
#define NGROUPS (NZ * NY * NXQ)   // 1,024,000 float4 groups

// --- persistent config: 256-thread blocks, z-quads ---
#define CT_BS 256
#define CT_NTHREADS (NGROUPS / 4)        // 256,000 (4 planes each)
#define CT_NBLOCKS (CT_NTHREADS / CT_BS) // 1000
#define BPQ 25                           // blocks per z-quad slab (6400/256)

typedef float f32x4 __attribute__((ext_vector_type(4)));

// ---- sync state (zero-init at module load) ----
__device__ unsigned int g_flag[CT_NBLOCKS * 16];   // one flag per 64B line
__device__ unsigned int g_xcdmap[CT_NBLOCKS];      // per-block physical XCC id

// Scoped-load/store asm (flg = "" / " sc0" / " sc1").
#define GLD4(dst, voff, base, flg) \
    asm volatile("global_load_dwordx4 %0, %1, %2" flg \
                 : "=v"(dst) : "v"(voff), "s"(base))
#define GLD1(dst, voff, base, flg) \
    asm volatile("global_load_dword %0, %1, %2" flg \
                 : "=v"(dst) : "v"(voff), "s"(base))
#define GST4(voff, val, base, flg) \
    asm volatile("global_store_dwordx4 %0, %1, %2" flg \
                 :: "v"(voff), "v"(val), "s"(base) : "memory")

__device__ __forceinline__ f32x4 ld4v(const float* p) {
    return *reinterpret_cast<const f32x4*>(p);
}

// One Euler step for a float4 column (identical FP order to all prior rounds).
__device__ __forceinline__ f32x4 step_cell(
    f32x4 cc, f32x4 ym, f32x4 yp, f32x4 zm, f32x4 zp,
    float xl, float xr, f32x4 tm, float D, float rho, float delta_t)
{
    f32x4 o;
    float lap, g;
    lap = xl    + cc[1] + ym[0] + yp[0] + zm[0] + zp[0] - 6.f * cc[0];
    g   = D * lap + rho * cc[0] * (1.f - cc[0]) - 2.f * tm[0] * cc[0];
    o[0] = fminf(fmaxf(cc[0] + g * delta_t, 0.f), 1.f);
    lap = cc[0] + cc[2] + ym[1] + yp[1] + zm[1] + zp[1] - 6.f * cc[1];
    g   = D * lap + rho * cc[1] * (1.f - cc[1]) - 2.f * tm[1] * cc[1];
    o[1] = fminf(fmaxf(cc[1] + g * delta_t, 0.f), 1.f);
    lap = cc[1] + cc[3] + ym[2] + yp[2] + zm[2] + zp[2] - 6.f * cc[2];
    g   = D * lap + rho * cc[2] * (1.f - cc[2]) - 2.f * tm[2] * cc[2];
    o[2] = fminf(fmaxf(cc[2] + g * delta_t, 0.f), 1.f);
    lap = cc[2] + xr    + ym[3] + yp[3] + zm[3] + zp[3] - 6.f * cc[3];
    g   = D * lap + rho * cc[3] * (1.f - cc[3]) - 2.f * tm[3] * cc[3];
    o[3] = fminf(fmaxf(cc[3] + g * delta_t, 0.f), 1.f);
    return o;
}

// ---------------- scoped-coherence all-steps kernel ----------------
__global__ __launch_bounds__(CT_BS, 4) void therapy_all(
    const float* __restrict__ c_init,
    const float* __restrict__ ther,
    float* __restrict__ out,
    float* __restrict__ ws,
    const float* __restrict__ Dp,
    const float* __restrict__ rhop,
    const float* __restrict__ dtp,
    const int* __restrict__ stepsp)
{
    __shared__ float2 lx[4][CT_BS];   // per-plane {x0 (reader's xr), x3 (xl)}

    // Bijective XCD swizzle (1000 % 8 == 0): each XCD owns 125 contiguous
    // logical blocks = 5 whole z-quad slabs (locality only; correctness
    // comes from the runtime link classification below).
    const int lb = (blockIdx.x & 7) * (CT_NBLOCKS / 8) + (blockIdx.x >> 3);
    const int tx = threadIdx.x;
    const int tid = lb * CT_BS + tx;

    const int xq = tid % NXQ;           // 0..39
    const int t2 = tid / NXQ;
    const int y  = t2 % NY;             // 0..159
    const int q  = lb / BPQ;            // z-quad index, block-uniform (0..39)

    const int   steps   = *stepsp;
    const float D       = *Dp;
    const float rho     = *rhop;
    const float delta_t = *dtp / (float)steps;

    const unsigned int fbase =
        __hip_atomic_load(&g_flag[lb * 16], __ATOMIC_RELAXED,
                          __HIP_MEMORY_SCOPE_AGENT);

    const int  offym = (y > 0)        ? -NX : 0;
    const int  offyp = (y < NY - 1)   ?  NX : 0;
    const int  offxl = (xq > 0)       ? -1  : 0;
    const bool mym = (y == 0), myp = (y == NY - 1);
    const bool mxl = (xq == 0), mxr = (xq == NXQ - 1);
    const bool mzm = (q == 0);
    const bool mzp = (q == 39);

    const int b0 = ((4 * q) * NY + y) * NX + 4 * xq;   // plane 4q (floats)
    const int b3 = b0 + 3 * NPLANE;                    // plane 4q+3

    const unsigned o_c  = (unsigned)b0 * 4u;
    const unsigned o_ym = (unsigned)(b0 + offym) * 4u;
    const unsigned o_yp = (unsigned)(b0 + offyp) * 4u;
    const unsigned o_xl = (unsigned)(b0 + offxl) * 4u;
    const unsigned o_xr = (unsigned)(b0 + (mxr ? 3 : 4)) * 4u;
    const unsigned o_zm = (unsigned)(b0 + (mzm ? 0 : -NPLANE)) * 4u;
    const unsigned o_zp = (unsigned)(b3 + (mzp ? 0 :  NPLANE)) * 4u;

    f32x4 tv[4], cv[4];
#pragma unroll
    for (int p = 0; p < 4; ++p) {
        tv[p] = ld4v(ther   + b0 + p * NPLANE);
        cv[p] = ld4v(c_init + b0 + p * NPLANE);
    }

    // ---- prologue: publish physical XCC id, handshake, classify links ----
    unsigned int myx;
    asm volatile("s_getreg_b32 %0, hwreg(HW_REG_XCC_ID)" : "=s"(myx));
    if (tx == 0) {
        __hip_atomic_store(&g_xcdmap[lb], myx, __ATOMIC_RELAXED,
                           __HIP_MEMORY_SCOPE_AGENT);
        asm volatile("s_waitcnt vmcnt(0)" ::: "memory");
        __hip_atomic_store(&g_flag[lb * 16], fbase + 1u, __ATOMIC_RELAXED,
                           __HIP_MEMORY_SCOPE_AGENT);
    }
    if (tx < 4) {
        const int d = (tx == 0) ? -BPQ : (tx == 1) ? -1 : (tx == 2) ? 1 : BPQ;
        int nb = lb + d;
        nb = nb < 0 ? 0 : (nb >= CT_NBLOCKS ? CT_NBLOCKS - 1 : nb);
        while (__hip_atomic_load(&g_flag[nb * 16], __ATOMIC_RELAXED,
                                 __HIP_MEMORY_SCOPE_AGENT) < fbase + 1u) {
            __builtin_amdgcn_s_sleep(2);
        }
    }
    __syncthreads();

    #define MAPLD(b) __hip_atomic_load(&g_xcdmap[(b)], __ATOMIC_RELAXED, \
                                       __HIP_MEMORY_SCOPE_AGENT)
    const unsigned xm25 = (lb >= BPQ)              ? MAPLD(lb - BPQ) : myx;
    const unsigned xm1  = (lb >= 1)                ? MAPLD(lb - 1)   : myx;
    const unsigned xp1  = (lb < CT_NBLOCKS - 1)    ? MAPLD(lb + 1)   : myx;
    const unsigned xp25 = (lb < CT_NBLOCKS - BPQ)  ? MAPLD(lb + BPQ) : myx;

    const bool zmX = (xm25 != myx);
    const bool zpX = (xp25 != myx);
    const bool ymX = (tx < NXQ)          && (xm1 != myx);
    const bool ypX = (tx >= CT_BS - NXQ) && (xp1 != myx);
    const bool xlX = (tx == 0)           && (xm1 != myx);
    const bool xrX = (tx == CT_BS - 1)   && (xp1 != myx);
    const bool stYX = (tx < NXQ && xm1 != myx) ||
                      (tx >= CT_BS - NXQ && xp1 != myx);
    const bool st0X = stYX || zmX;
    const bool st3X = stYX || zpX;

    const float* rd = c_init;
    for (int i = 0; i < steps; ++i) {
        // Ping-pong: align so step steps-1 lands in out.
        float* wr = (((steps - 1 - i) & 1) == 0) ? out : ws;

        // A: publish x-exchange values (previous-step cv == rd values)
#pragma unroll
        for (int p = 0; p < 4; ++p)
            lx[p][tx] = make_float2(cv[p][0], cv[p][3]);

        // B: wait for the 4 dependency blocks to have finished step i-1
        //    (RAW: their step i-1 outputs; WAR: they are done reading the
        //     buffer this step overwrites — ping-pong safety)
        if (i > 0 && tx < 4) {
            const int d = (tx == 0) ? -BPQ : (tx == 1) ? -1
                        : (tx == 2) ?    1 : BPQ;
            int nb = lb + d;
            nb = nb < 0 ? 0 : (nb >= CT_NBLOCKS ? CT_NBLOCKS - 1 : nb);
            const unsigned tgt = fbase + 1u + (unsigned)i;
            while (__hip_atomic_load(&g_flag[nb * 16], __ATOMIC_RELAXED,
                                     __HIP_MEMORY_SCOPE_AGENT) < tgt) {
                __builtin_amdgcn_s_sleep(2);
            }
        }
        __syncthreads();

        // C: neighbor loads (sc0 = own-XCD L2; sc1 = cross-XCD via IC)
        f32x4 ym[4], yp[4], zmg, zpg;
#pragma unroll
        for (int p = 0; p < 4; ++p) {
            const unsigned po = (unsigned)(p * NPLANE * 4);
            if (ymX) { GLD4(ym[p], o_ym + po, rd, " sc1"); }
            else     { GLD4(ym[p], o_ym + po, rd, " sc0"); }
            if (ypX) { GLD4(yp[p], o_yp + po, rd, " sc1"); }
            else     { GLD4(yp[p], o_yp + po, rd, " sc0"); }
        }
        if (zmX) { GLD4(zmg, o_zm, rd, " sc1"); } else { GLD4(zmg, o_zm, rd, " sc0"); }
        if (zpX) { GLD4(zpg, o_zp, rd, " sc1"); } else { GLD4(zpg, o_zp, rd, " sc0"); }
        float xl[4], xr[4];
        if (tx == 0) {
#pragma unroll
            for (int p = 0; p < 4; ++p) {
                const unsigned po = (unsigned)(p * NPLANE * 4);
                if (xlX) { GLD1(xl[p], o_xl + po, rd, " sc1"); }
                else     { GLD1(xl[p], o_xl + po, rd, " sc0"); }
            }
        } else {
#pragma unroll
            for (int p = 0; p < 4; ++p) xl[p] = lx[p][tx - 1].y;
        }
        if (tx == CT_BS - 1) {
#pragma unroll
            for (int p = 0; p < 4; ++p) {
                const unsigned po = (unsigned)(p * NPLANE * 4);
                if (xrX) { GLD1(xr[p], o_xr + po, rd, " sc1"); }
                else     { GLD1(xr[p], o_xr + po, rd, " sc0"); }
            }
        } else {
#pragma unroll
            for (int p = 0; p < 4; ++p) xr[p] = lx[p][tx + 1].x;
        }
        asm volatile("s_waitcnt vmcnt(0)" ::: "memory");
        __builtin_amdgcn_sched_barrier(0);

        // D: boundary masks + compute (internal z-faces from registers)
        const f32x4 z4 = {0.f, 0.f, 0.f, 0.f};
        if (mym) {
#pragma unroll
            for (int p = 0; p < 4; ++p) ym[p] = z4;
        }
        if (myp) {
#pragma unroll
            for (int p = 0; p < 4; ++p) yp[p] = z4;
        }
        if (mzm) zmg = z4;
        if (mzp) zpg = z4;
        if (mxl) {
#pragma unroll
            for (int p = 0; p < 4; ++p) xl[p] = 0.f;
        }
        if (mxr) {
#pragma unroll
            for (int p = 0; p < 4; ++p) xr[p] = 0.f;
        }

        f32x4 n[4];
        n[0] = step_cell(cv[0], ym[0], yp[0], zmg,   cv[1], xl[0], xr[0], tv[0], D, rho, delta_t);
        n[1] = step_cell(cv[1], ym[1], yp[1], cv[0], cv[2], xl[1], xr[1], tv[1], D, rho, delta_t);
        n[2] = step_cell(cv[2], ym[2], yp[2], cv[1], cv[3], xl[2], xr[2], tv[2], D, rho, delta_t);
        n[3] = step_cell(cv[3], ym[3], yp[3], cv[2], zpg,   xl[3], xr[3], tv[3], D, rho, delta_t);

        // E: stores (interior stay dirty in local L2; cross-read cells sc1)
        if (st0X) { GST4(o_c, n[0], wr, " sc1"); } else { GST4(o_c, n[0], wr, ""); }
        if (stYX) { GST4(o_c + 102400u, n[1], wr, " sc1"); }
        else      { GST4(o_c + 102400u, n[1], wr, ""); }
        if (stYX) { GST4(o_c + 204800u, n[2], wr, " sc1"); }
        else      { GST4(o_c + 204800u, n[2], wr, ""); }
        if (st3X) { GST4(o_c + 307200u, n[3], wr, " sc1"); }
        else      { GST4(o_c + 307200u, n[3], wr, ""); }

        // F: drain stores (syncthreads emits per-wave vmcnt(0) before
        //    s_barrier) then post progress with a relaxed agent store.
        __syncthreads();
        if (tx == 0) {
            __hip_atomic_store(&g_flag[lb * 16], fbase + 2u + (unsigned)i,
                               __ATOMIC_RELAXED, __HIP_MEMORY_SCOPE_AGENT);
        }

#pragma unroll
        for (int p = 0; p < 4; ++p) cv[p] = n[p];
        rd = wr;
    }
}

extern "C" void kernel_launch(void* const* d_in, const int* in_sizes, int n_in,
                              void* d_out, int out_size, void* d_ws, size_t ws_size,
                              hipStream_t stream) {
    const float* c_init = (const float*)d_in[0];
    const float* Dp     = (const float*)d_in[1];
    const float* rhop   = (const float*)d_in[2];
    const float* dtp    = (const float*)d_in[3];
    const float* ther   = (const float*)d_in[4];
    const int*   stepsp = (const int*)d_in[5];

    float* out = (float*)d_out;
    float* wsA = (float*)d_ws;   // grid buffer (16.4 MB)

    // NO runtime API calls here (graph-capture-safe). Co-residency is
    // compile-time guaranteed by __launch_bounds__(256,4): >=1024 blocks
    // co-resident >= 1000 launched.
    therapy_all<<<dim3(CT_NBLOCKS), dim3(CT_BS), 0, stream>>>(
        c_init, ther, out, wsA, Dp, rhop, dtp, stepsp);
}